// Round 11
// baseline (1476.407 us; speedup 1.0000x reference)
//
#include <hip/hip_runtime.h>
#include <hip/hip_bf16.h>
#include <cstdint>
#include <cstddef>

typedef __bf16 bf16_t;
typedef __bf16 bf16x4_v __attribute__((ext_vector_type(4)));
typedef __bf16 bf16x8_v __attribute__((ext_vector_type(8)));
typedef float  f32x4_v  __attribute__((ext_vector_type(4)));

// async global->LDS, 16B/lane; LDS dest = wave-uniform base + lane*16
__device__ __forceinline__ void gll16(const void* g, void* l) {
  __builtin_amdgcn_global_load_lds(
      (const __attribute__((address_space(1))) void*)g,
      (__attribute__((address_space(3))) void*)l, 16, 0, 0);
}

// raw barrier: does NOT drain vmcnt (unlike __syncthreads)
#define BARRIER()  asm volatile("s_barrier" ::: "memory")
#define WAIT_VM(N) asm volatile("s_waitcnt vmcnt(" #N ")" ::: "memory")

__device__ __forceinline__ float gelu_tanh(float x) {
  // 0.5x(1+tanh(z)) == x * sigmoid(2z); NaN-free at extremes
  float z = 0.79788456080286535588f * (x + 0.044715f * x * x * x);
  return x / (1.0f + __expf(-2.0f * z));
}

// ---------------------------------------------------------------- LayerNorm
__global__ __launch_bounds__(256) void ln_kernel(
    const float* __restrict__ X, const float* __restrict__ sc,
    const float* __restrict__ off, bf16_t* __restrict__ Y)
{
  const int row = blockIdx.x;
  const int tid = threadIdx.x;
  const float4 v = *(const float4*)&X[(size_t)row * 1024 + tid * 4];
  float s  = v.x + v.y + v.z + v.w;
  float s2 = v.x * v.x + v.y * v.y + v.z * v.z + v.w * v.w;
#pragma unroll
  for (int m = 1; m < 64; m <<= 1) {
    s  += __shfl_xor(s, m);
    s2 += __shfl_xor(s2, m);
  }
  __shared__ float red[8];
  const int wid = tid >> 6;
  if ((tid & 63) == 0) { red[wid] = s; red[4 + wid] = s2; }
  __syncthreads();
  s  = red[0] + red[1] + red[2] + red[3];
  s2 = red[4] + red[5] + red[6] + red[7];
  const float mu  = s * (1.0f / 1024.0f);
  float var = s2 * (1.0f / 1024.0f) - mu * mu;
  var = fmaxf(var, 0.0f);
  const float rs = rsqrtf(var + 1e-5f);
  const float4 g = *(const float4*)&sc[tid * 4];
  const float4 o = *(const float4*)&off[tid * 4];
  bf16x4_v y;
  y[0] = (bf16_t)((v.x - mu) * rs * g.x + o.x);
  y[1] = (bf16_t)((v.y - mu) * rs * g.y + o.y);
  y[2] = (bf16_t)((v.z - mu) * rs * g.z + o.z);
  y[3] = (bf16_t)((v.w - mu) * rs * g.w + o.w);
  *(bf16x4_v*)&Y[(size_t)row * 1024 + tid * 4] = y;
}

// ------------------------------------------------------- transpose f32->bf16
__global__ __launch_bounds__(256) void transpose_kernel(
    const float* __restrict__ Win, bf16_t* __restrict__ Wt, int R, int C)
{
  __shared__ float t[32][33];
  const int tx = threadIdx.x & 31;
  const int ty = (threadIdx.x >> 5) << 2;
  const int r0 = blockIdx.y * 32;
  const int c0 = blockIdx.x * 32;
#pragma unroll
  for (int r = 0; r < 4; ++r)
    t[ty + r][tx] = Win[(size_t)(r0 + ty + r) * C + (c0 + tx)];
  __syncthreads();
#pragma unroll
  for (int r = 0; r < 4; ++r)
    Wt[(size_t)(c0 + ty + r) * R + (r0 + tx)] = (bf16_t)t[tx][ty + r];
}

// ------------------------------------------------- 256x256x64 8-wave GEMM
// R10 structure: TWO barriers per K-tile at the vmcnt publication points
//  - ph1-end (vmcnt(8)+barrier): publishes prev-tile Aq1/Aq3 for ph2/ph3
//  - ph3-end (vmcnt(2)+barrier): publishes B q0-3 + Aq0/Aq2 for next tile,
//    WAR fence before buffer re-staging.
// This round: 2-tile unroll with LITERAL LDS buffer indices (kills the
// runtime `cur` toggle's per-phase address VALU), branch-free steady loop,
// peeled tail. LDS col-swizzle byte ^= ((row&7)<<4) on gll source + ds_read
// addr; kk's 64B step inside the XOR (cs0/cs1).

#define LOADA(DST, I0)                                                        \
  _Pragma("unroll") for (int di_ = 0; di_ < 2; ++di_) {                       \
    DST[di_][0] = *(const bf16x8_v*)(Ab + arow + ((I0) + di_) * 2048 + cs0);  \
    DST[di_][1] = *(const bf16x8_v*)(Ab + arow + ((I0) + di_) * 2048 + cs1);  \
  }

#define MFMA2(AV, I0)                                                         \
  __builtin_amdgcn_s_setprio(1);                                              \
  _Pragma("unroll") for (int di_ = 0; di_ < 2; ++di_)                         \
  _Pragma("unroll") for (int kk_ = 0; kk_ < 2; ++kk_)                         \
  _Pragma("unroll") for (int j_ = 0; j_ < 4; ++j_)                            \
    acc[(I0) + di_][j_] = __builtin_amdgcn_mfma_f32_16x16x32_bf16(            \
        AV[di_][kk_], bfrag[j_][kk_], acc[(I0) + di_][j_], 0, 0, 0);          \
  __builtin_amdgcn_s_setprio(0);

#define ISSUE_A(NB, F, Q)                                                     \
  gll16(Asrc + ((size_t)(Q) * 64 * 4096) + (size_t)(F) * 64,                  \
        (char*)(&As[NB][0]) + (Q) * 8192 + ldsdst)
#define ISSUE_B(NB, F, Q)                                                     \
  gll16(Bsrc + ((size_t)(Q) * 64 * 4096) +                                    \
            (MODE == 1 ? ((((F) * 64) + rolloff) & 4095) : ((F) * 64)),       \
        (char*)(&Bs[NB][0]) + (Q) * 8192 + ldsdst)

// one K-tile, 2-barrier body; CA/CB literal buffer indices, F tile idx,
// ST stage-next?, W1M = vmcnt at ph1-end (8 steady / 0 final)
#define TILE2(CA, CB, F, ST, W1M)                                             \
  {                                                                           \
    const char* Ab = (const char*)&As[CA][0];                                 \
    const char* Bb = (const char*)&Bs[CA][0];                                 \
    { /* ph0: all B frags + A i0,1; stage next B q0-3; MFMA (no barrier) */   \
      _Pragma("unroll") for (int j_ = 0; j_ < 4; ++j_) {                      \
        bfrag[j_][0] = *(const bf16x8_v*)(Bb + brow + j_ * 2048 + cs0);       \
        bfrag[j_][1] = *(const bf16x8_v*)(Bb + brow + j_ * 2048 + cs1);       \
      }                                                                       \
      bf16x8_v av[2][2];                                                      \
      LOADA(av, 0);                                                           \
      if (ST) { ISSUE_B(CB, (F) + 1, 0); ISSUE_B(CB, (F) + 1, 1);             \
                ISSUE_B(CB, (F) + 1, 2); ISSUE_B(CB, (F) + 1, 3); }           \
      MFMA2(av, 0);                                                           \
    }                                                                         \
    { /* ph1: A i2,3; stage next A q0,q2,q1,q3; MFMA; publish prev Aq1/Aq3 */ \
      bf16x8_v av[2][2];                                                      \
      LOADA(av, 2);                                                           \
      if (ST) { ISSUE_A(CB, (F) + 1, 0); ISSUE_A(CB, (F) + 1, 2);             \
                ISSUE_A(CB, (F) + 1, 1); ISSUE_A(CB, (F) + 1, 3); }           \
      MFMA2(av, 2);                                                           \
      WAIT_VM(W1M);                                                           \
      BARRIER();                                                              \
    }                                                                         \
    { /* ph2: A i4,5; MFMA (no barrier) */                                    \
      bf16x8_v av[2][2];                                                      \
      LOADA(av, 4);                                                           \
      MFMA2(av, 4);                                                           \
    }                                                                         \
    { /* ph3: A i6,7; MFMA; publish next buffer (counted) */                  \
      bf16x8_v av[2][2];                                                      \
      LOADA(av, 6);                                                           \
      MFMA2(av, 6);                                                           \
      if (ST) WAIT_VM(2);                                                     \
      BARRIER();                                                              \
    }                                                                         \
  }

template<int MODE>
__global__ __launch_bounds__(512, 2) void gemm256_kernel(
    const bf16_t* __restrict__ Ag, const bf16_t* __restrict__ Bg,
    const float* __restrict__ bias, const float* __restrict__ Xres,
    void* __restrict__ Out, long rowbase)
{
  __shared__ __align__(16) bf16_t As[2][256 * 64];
  __shared__ __align__(16) bf16_t Bs[2][256 * 64];

  const int tid  = threadIdx.x;
  const int lane = tid & 63;
  const int wid  = tid >> 6;
  const int wm   = wid >> 2;   // 0..1
  const int wn   = wid & 3;    // 0..3

  // XCD-bijective block swizzle (nwg % 8 == 0 by construction)
  const int nwgx = gridDim.x;
  const int nwg  = nwgx * gridDim.y;
  const int flat = blockIdx.y * nwgx + blockIdx.x;
  const int swz  = (flat & 7) * (nwg >> 3) + (flat >> 3);
  const int bm   = swz % nwgx;
  const int bnl  = swz / nwgx;

  int kgrp = 0, m0, rolloff = 0;
  if (MODE == 1) { kgrp = bnl >> 4; m0 = (bnl & 15) << 8; rolloff = ((4 - kgrp) & 3) << 10; }
  else           { m0 = bnl << 8; }

  // staging: thread covers LDS bytes q*8192 + tid*16 -> row=tid/8+q*64, colbyte=(tid&7)*16
  const int trow = tid >> 3;
  const int scb  = (((tid & 7) ^ (trow & 7)) << 4);
  const bf16_t* Asrc = Ag + (size_t)(bm * 256 + trow) * 4096 + (scb >> 1);
  const bf16_t* Bsrc = Bg + (size_t)(m0 + trow) * 4096 + (scb >> 1);
  const int ldsdst = (wid << 10);

  // fragment read offsets (bytes); row&7 == lane&7 for all fragment rows
  const int arow = (wm * 128 + (lane & 15)) * 128;
  const int brow = (wn * 64  + (lane & 15)) * 128;
  const int cs0  = (((lane >> 4) << 4)     ) ^ ((lane & 7) << 4);
  const int cs1  = (((lane >> 4) << 4) | 64) ^ ((lane & 7) << 4);

  f32x4_v  acc[8][4] = {};
  bf16x8_v bfrag[4][2];

  // prologue: stage tile 0 in steady-state order
  ISSUE_B(0, 0, 0); ISSUE_B(0, 0, 1); ISSUE_B(0, 0, 2); ISSUE_B(0, 0, 3);
  ISSUE_A(0, 0, 0); ISSUE_A(0, 0, 2); ISSUE_A(0, 0, 1); ISSUE_A(0, 0, 3);
  WAIT_VM(2);   // B q0-3, A q0, q2 landed; A q1, q3 in flight (needed ph2+)
  BARRIER();

#pragma unroll 1
  for (int t = 0; t < 62; t += 2) {
    TILE2(0, 1, t,     1, 8);
    TILE2(1, 0, t + 1, 1, 8);
  }
  TILE2(0, 1, 62, 1, 8);
  TILE2(1, 0, 63, 0, 0);

  const int cb16 = lane & 15;
  const int r4   = (lane >> 4) << 2;
  if (MODE == 1) {
    bf16_t* H = (bf16_t*)Out;
#pragma unroll
    for (int j = 0; j < 4; ++j) {
      const int m = m0 + wn * 64 + j * 16 + cb16;
      const float bv = bias[m];
#pragma unroll
      for (int i = 0; i < 8; ++i) {
        const int browi = bm * 256 + wm * 128 + i * 16 + r4;
#pragma unroll
        for (int r = 0; r < 4; ++r) {
          float v = acc[i][j][r] + bv;
          H[((size_t)(browi + r) * 4 + kgrp) * 4096 + m] = (bf16_t)gelu_tanh(v);
        }
      }
    }
  } else {
    float* O = (float*)Out;
#pragma unroll
    for (int j = 0; j < 4; ++j) {
      const int w = m0 + wn * 64 + j * 16 + cb16;
      const float bv = bias[w];
#pragma unroll
      for (int i = 0; i < 8; ++i) {
        const long row = rowbase + bm * 256 + wm * 128 + i * 16 + r4;
#pragma unroll
        for (int r = 0; r < 4; ++r)
          O[(size_t)(row + r) * 1024 + w] =
              Xres[(size_t)(row + r) * 1024 + w] + acc[i][j][r] + bv;
      }
    }
  }
}

// ----------------------------------------------------------------- launch
extern "C" void kernel_launch(void* const* d_in, const int* in_sizes, int n_in,
                              void* d_out, int out_size, void* d_ws, size_t ws_size,
                              hipStream_t stream)
{
  const float* x   = (const float*)d_in[0];
  const float* lns = (const float*)d_in[1];
  const float* lno = (const float*)d_in[2];
  const float* W1  = (const float*)d_in[3];
  const float* b1  = (const float*)d_in[4];
  const float* W2  = (const float*)d_in[5];
  const float* b2  = (const float*)d_in[6];
  float* out = (float*)d_out;

  char* ws = (char*)d_ws;
  const size_t W1OFF = (size_t)64 << 20;   // Y: 64 MB
  const size_t W2OFF = (size_t)96 << 20;   // W1t: 32 MB
  const size_t HOFF  = (size_t)104 << 20;  // W2t: 8 MB
  bf16_t* Y   = (bf16_t*)(ws);
  bf16_t* W1t = (bf16_t*)(ws + W1OFF);
  bf16_t* W2t = (bf16_t*)(ws + W2OFF);
  bf16_t* H   = (bf16_t*)(ws + HOFF);

  ln_kernel<<<32768, 256, 0, stream>>>(x, lns, lno, Y);
  transpose_kernel<<<dim3(128, 128), 256, 0, stream>>>(W1, W1t, 4096, 4096);
  transpose_kernel<<<dim3(32, 128), 256, 0, stream>>>(W2, W2t, 4096, 1024);

  const size_t per_row = (size_t)4 * 4096 * 2;
  long chunk = 8192;
  if (ws_size < HOFF + (size_t)8192 * per_row) {
    long maxb = (long)((ws_size - HOFF) / per_row);
    chunk = maxb & ~255L;
    if (chunk < 256) chunk = 256;
  }
  for (long b0 = 0; b0 < 8192; b0 += chunk) {
    const long cb = (8192 - b0 < chunk) ? (8192 - b0) : chunk;
    gemm256_kernel<1><<<dim3(cb / 256, 64), 512, 0, stream>>>(
        Y + (size_t)b0 * 4096, W1t, b1, nullptr, (void*)H, 0);
    gemm256_kernel<2><<<dim3((cb * 4) / 256, 4), 512, 0, stream>>>(
        H, W2t, b2, x, (void*)out, b0 * 4);
  }
}

// Round 12
// 1415.475 us; speedup vs baseline: 1.0430x; 1.0430x over previous
//
#include <hip/hip_runtime.h>
#include <hip/hip_bf16.h>
#include <cstdint>
#include <cstddef>

typedef __bf16 bf16_t;
typedef __bf16 bf16x4_v __attribute__((ext_vector_type(4)));
typedef __bf16 bf16x8_v __attribute__((ext_vector_type(8)));
typedef float  f32x4_v  __attribute__((ext_vector_type(4)));

// async global->LDS, 16B/lane; LDS dest = wave-uniform base + lane*16
__device__ __forceinline__ void gll16(const void* g, void* l) {
  __builtin_amdgcn_global_load_lds(
      (const __attribute__((address_space(1))) void*)g,
      (__attribute__((address_space(3))) void*)l, 16, 0, 0);
}

// raw barrier: does NOT drain vmcnt (unlike __syncthreads)
#define BARRIER()  asm volatile("s_barrier" ::: "memory")
#define WAIT_VM(N) asm volatile("s_waitcnt vmcnt(" #N ")" ::: "memory")

__device__ __forceinline__ float gelu_tanh(float x) {
  // 0.5x(1+tanh(z)) == x * sigmoid(2z); NaN-free at extremes
  float z = 0.79788456080286535588f * (x + 0.044715f * x * x * x);
  return x / (1.0f + __expf(-2.0f * z));
}

// ---------------------------------------------------------------- LayerNorm
__global__ __launch_bounds__(256) void ln_kernel(
    const float* __restrict__ X, const float* __restrict__ sc,
    const float* __restrict__ off, bf16_t* __restrict__ Y)
{
  const int row = blockIdx.x;
  const int tid = threadIdx.x;
  const float4 v = *(const float4*)&X[(size_t)row * 1024 + tid * 4];
  float s  = v.x + v.y + v.z + v.w;
  float s2 = v.x * v.x + v.y * v.y + v.z * v.z + v.w * v.w;
#pragma unroll
  for (int m = 1; m < 64; m <<= 1) {
    s  += __shfl_xor(s, m);
    s2 += __shfl_xor(s2, m);
  }
  __shared__ float red[8];
  const int wid = tid >> 6;
  if ((tid & 63) == 0) { red[wid] = s; red[4 + wid] = s2; }
  __syncthreads();
  s  = red[0] + red[1] + red[2] + red[3];
  s2 = red[4] + red[5] + red[6] + red[7];
  const float mu  = s * (1.0f / 1024.0f);
  float var = s2 * (1.0f / 1024.0f) - mu * mu;
  var = fmaxf(var, 0.0f);
  const float rs = rsqrtf(var + 1e-5f);
  const float4 g = *(const float4*)&sc[tid * 4];
  const float4 o = *(const float4*)&off[tid * 4];
  bf16x4_v y;
  y[0] = (bf16_t)((v.x - mu) * rs * g.x + o.x);
  y[1] = (bf16_t)((v.y - mu) * rs * g.y + o.y);
  y[2] = (bf16_t)((v.z - mu) * rs * g.z + o.z);
  y[3] = (bf16_t)((v.w - mu) * rs * g.w + o.w);
  *(bf16x4_v*)&Y[(size_t)row * 1024 + tid * 4] = y;
}

// ------------------------------------------------------- transpose f32->bf16
__global__ __launch_bounds__(256) void transpose_kernel(
    const float* __restrict__ Win, bf16_t* __restrict__ Wt, int R, int C)
{
  __shared__ float t[32][33];
  const int tx = threadIdx.x & 31;
  const int ty = (threadIdx.x >> 5) << 2;
  const int r0 = blockIdx.y * 32;
  const int c0 = blockIdx.x * 32;
#pragma unroll
  for (int r = 0; r < 4; ++r)
    t[ty + r][tx] = Win[(size_t)(r0 + ty + r) * C + (c0 + tx)];
  __syncthreads();
#pragma unroll
  for (int r = 0; r < 4; ++r)
    Wt[(size_t)(c0 + ty + r) * R + (r0 + tx)] = (bf16_t)t[tx][ty + r];
}

// ------------------------------------------------- 256x256x64 8-wave GEMM
// FINAL (R10): TWO barriers per K-tile, exactly at the vmcnt publication
// points. Hazard audit:
//  - ph1-end (vmcnt(8)+barrier): publishes prev-tile Aq1/Aq3 for ph2/ph3
//    fragment reads (wm0 reads q1, wm1 reads q3) — cross-wave, required.
//  - ph3-end (vmcnt(2)+barrier): publishes B q0-3 + Aq0/Aq2 for next tile's
//    ph0/ph1 reads, and is the WAR fence before that buffer is re-staged.
//  - ph0-end / ph2-end barriers publish nothing — removed (R9/R10 wins:
//    8->4->2 barriers = MfmaUtil 42.6 -> 47 -> 50).
// Audited-and-rejected: 2-tile unroll (R8/R11: −7% both barrier densities),
// lgkmcnt-pin (R6), C-quadrant held-frag phases (R5), 32x32 MFMA (R7:
// 4-way LDS conflicts from lane&31 rows vs 8-slot row-XOR swizzle).
// LDS col-swizzle byte ^= ((row&7)<<4) on gll source + ds_read addr; kk's
// 64B step inside the XOR (cs0/cs1) — bit-6 carry would cross rows.

#define LOADA(DST, I0)                                                        \
  _Pragma("unroll") for (int di_ = 0; di_ < 2; ++di_) {                       \
    DST[di_][0] = *(const bf16x8_v*)(Ab + arow + ((I0) + di_) * 2048 + cs0);  \
    DST[di_][1] = *(const bf16x8_v*)(Ab + arow + ((I0) + di_) * 2048 + cs1);  \
  }

#define MFMA2(AV, I0)                                                         \
  __builtin_amdgcn_s_setprio(1);                                              \
  _Pragma("unroll") for (int di_ = 0; di_ < 2; ++di_)                         \
  _Pragma("unroll") for (int kk_ = 0; kk_ < 2; ++kk_)                         \
  _Pragma("unroll") for (int j_ = 0; j_ < 4; ++j_)                            \
    acc[(I0) + di_][j_] = __builtin_amdgcn_mfma_f32_16x16x32_bf16(            \
        AV[di_][kk_], bfrag[j_][kk_], acc[(I0) + di_][j_], 0, 0, 0);          \
  __builtin_amdgcn_s_setprio(0);

#define ISSUE_A(NB, F, Q)                                                     \
  gll16(Asrc + ((size_t)(Q) * 64 * 4096) + (size_t)(F) * 64,                  \
        (char*)(&As[NB][0]) + (Q) * 8192 + ldsdst)
#define ISSUE_B(NB, F, Q)                                                     \
  gll16(Bsrc + ((size_t)(Q) * 64 * 4096) +                                    \
            (MODE == 1 ? ((((F) * 64) + rolloff) & 4095) : ((F) * 64)),       \
        (char*)(&Bs[NB][0]) + (Q) * 8192 + ldsdst)

template<int MODE>
__global__ __launch_bounds__(512, 2) void gemm256_kernel(
    const bf16_t* __restrict__ Ag, const bf16_t* __restrict__ Bg,
    const float* __restrict__ bias, const float* __restrict__ Xres,
    void* __restrict__ Out, long rowbase)
{
  __shared__ __align__(16) bf16_t As[2][256 * 64];
  __shared__ __align__(16) bf16_t Bs[2][256 * 64];

  const int tid  = threadIdx.x;
  const int lane = tid & 63;
  const int wid  = tid >> 6;
  const int wm   = wid >> 2;   // 0..1
  const int wn   = wid & 3;    // 0..3

  // XCD-bijective block swizzle (nwg % 8 == 0 by construction)
  const int nwgx = gridDim.x;
  const int nwg  = nwgx * gridDim.y;
  const int flat = blockIdx.y * nwgx + blockIdx.x;
  const int swz  = (flat & 7) * (nwg >> 3) + (flat >> 3);
  const int bm   = swz % nwgx;
  const int bnl  = swz / nwgx;

  int kgrp = 0, m0, rolloff = 0;
  if (MODE == 1) { kgrp = bnl >> 4; m0 = (bnl & 15) << 8; rolloff = ((4 - kgrp) & 3) << 10; }
  else           { m0 = bnl << 8; }

  // staging: thread covers LDS bytes q*8192 + tid*16 -> row=tid/8+q*64, colbyte=(tid&7)*16
  const int trow = tid >> 3;
  const int scb  = (((tid & 7) ^ (trow & 7)) << 4);
  const bf16_t* Asrc = Ag + (size_t)(bm * 256 + trow) * 4096 + (scb >> 1);
  const bf16_t* Bsrc = Bg + (size_t)(m0 + trow) * 4096 + (scb >> 1);
  const int ldsdst = (wid << 10);

  // fragment read offsets (bytes); row&7 == lane&7 for all fragment rows
  const int arow = (wm * 128 + (lane & 15)) * 128;
  const int brow = (wn * 64  + (lane & 15)) * 128;
  const int cs0  = (((lane >> 4) << 4)     ) ^ ((lane & 7) << 4);
  const int cs1  = (((lane >> 4) << 4) | 64) ^ ((lane & 7) << 4);

  f32x4_v  acc[8][4] = {};
  bf16x8_v bfrag[4][2];

  // prologue: stage tile 0 in steady-state order
  ISSUE_B(0, 0, 0); ISSUE_B(0, 0, 1); ISSUE_B(0, 0, 2); ISSUE_B(0, 0, 3);
  ISSUE_A(0, 0, 0); ISSUE_A(0, 0, 2); ISSUE_A(0, 0, 1); ISSUE_A(0, 0, 3);
  WAIT_VM(2);   // B q0-3, A q0, q2 landed; A q1, q3 in flight (needed ph2+)
  BARRIER();

  int cur = 0;
  for (int f = 0; f < 64; ++f) {
    const char* Ab = (const char*)&As[cur][0];
    const char* Bb = (const char*)&Bs[cur][0];
    const int  nb = cur ^ 1;
    const bool st = (f < 63);

    { // ph0: all B frags + A i0,1; stage next B q0-3; MFMA (no barrier)
#pragma unroll
      for (int j = 0; j < 4; ++j) {
        bfrag[j][0] = *(const bf16x8_v*)(Bb + brow + j * 2048 + cs0);
        bfrag[j][1] = *(const bf16x8_v*)(Bb + brow + j * 2048 + cs1);
      }
      bf16x8_v av[2][2];
      LOADA(av, 0);
      if (st) { ISSUE_B(nb, f + 1, 0); ISSUE_B(nb, f + 1, 1);
                ISSUE_B(nb, f + 1, 2); ISSUE_B(nb, f + 1, 3); }
      MFMA2(av, 0);
    }
    { // ph1: A i2,3; stage next A q0,q2,q1,q3; MFMA; publish prev Aq1/Aq3
      bf16x8_v av[2][2];
      LOADA(av, 2);
      if (st) { ISSUE_A(nb, f + 1, 0); ISSUE_A(nb, f + 1, 2);
                ISSUE_A(nb, f + 1, 1); ISSUE_A(nb, f + 1, 3); }
      MFMA2(av, 2);
      if (st) { WAIT_VM(8); } else { WAIT_VM(0); }
      BARRIER();
    }
    { // ph2: A i4,5; MFMA (no barrier)
      bf16x8_v av[2][2];
      LOADA(av, 4);
      MFMA2(av, 4);
    }
    { // ph3: A i6,7; MFMA; publish next buffer (counted)
      bf16x8_v av[2][2];
      LOADA(av, 6);
      MFMA2(av, 6);
      if (st) WAIT_VM(2);
      BARRIER();
    }
    cur = nb;
  }

  const int cb16 = lane & 15;
  const int r4   = (lane >> 4) << 2;
  if (MODE == 1) {
    bf16_t* H = (bf16_t*)Out;
#pragma unroll
    for (int j = 0; j < 4; ++j) {
      const int m = m0 + wn * 64 + j * 16 + cb16;
      const float bv = bias[m];
#pragma unroll
      for (int i = 0; i < 8; ++i) {
        const int browi = bm * 256 + wm * 128 + i * 16 + r4;
#pragma unroll
        for (int r = 0; r < 4; ++r) {
          float v = acc[i][j][r] + bv;
          H[((size_t)(browi + r) * 4 + kgrp) * 4096 + m] = (bf16_t)gelu_tanh(v);
        }
      }
    }
  } else {
    float* O = (float*)Out;
#pragma unroll
    for (int j = 0; j < 4; ++j) {
      const int w = m0 + wn * 64 + j * 16 + cb16;
      const float bv = bias[w];
#pragma unroll
      for (int i = 0; i < 8; ++i) {
        const long row = rowbase + bm * 256 + wm * 128 + i * 16 + r4;
#pragma unroll
        for (int r = 0; r < 4; ++r)
          O[(size_t)(row + r) * 1024 + w] =
              Xres[(size_t)(row + r) * 1024 + w] + acc[i][j][r] + bv;
      }
    }
  }
}

// ----------------------------------------------------------------- launch
extern "C" void kernel_launch(void* const* d_in, const int* in_sizes, int n_in,
                              void* d_out, int out_size, void* d_ws, size_t ws_size,
                              hipStream_t stream)
{
  const float* x   = (const float*)d_in[0];
  const float* lns = (const float*)d_in[1];
  const float* lno = (const float*)d_in[2];
  const float* W1  = (const float*)d_in[3];
  const float* b1  = (const float*)d_in[4];
  const float* W2  = (const float*)d_in[5];
  const float* b2  = (const float*)d_in[6];
  float* out = (float*)d_out;

  char* ws = (char*)d_ws;
  const size_t W1OFF = (size_t)64 << 20;   // Y: 64 MB
  const size_t W2OFF = (size_t)96 << 20;   // W1t: 32 MB
  const size_t HOFF  = (size_t)104 << 20;  // W2t: 8 MB
  bf16_t* Y   = (bf16_t*)(ws);
  bf16_t* W1t = (bf16_t*)(ws + W1OFF);
  bf16_t* W2t = (bf16_t*)(ws + W2OFF);
  bf16_t* H   = (bf16_t*)(ws + HOFF);

  ln_kernel<<<32768, 256, 0, stream>>>(x, lns, lno, Y);
  transpose_kernel<<<dim3(128, 128), 256, 0, stream>>>(W1, W1t, 4096, 4096);
  transpose_kernel<<<dim3(32, 128), 256, 0, stream>>>(W2, W2t, 4096, 1024);

  const size_t per_row = (size_t)4 * 4096 * 2;
  long chunk = 8192;
  if (ws_size < HOFF + (size_t)8192 * per_row) {
    long maxb = (long)((ws_size - HOFF) / per_row);
    chunk = maxb & ~255L;
    if (chunk < 256) chunk = 256;
  }
  for (long b0 = 0; b0 < 8192; b0 += chunk) {
    const long cb = (8192 - b0 < chunk) ? (8192 - b0) : chunk;
    gemm256_kernel<1><<<dim3(cb / 256, 64), 512, 0, stream>>>(
        Y + (size_t)b0 * 4096, W1t, b1, nullptr, (void*)H, 0);
    gemm256_kernel<2><<<dim3((cb * 4) / 256, 4), 512, 0, stream>>>(
        H, W2t, b2, x, (void*)out, b0 * 4);
  }
}